// Round 4
// baseline (2245.140 us; speedup 1.0000x reference)
//
#include <hip/hip_runtime.h>

// ---------------------------------------------------------------------------
// GCN 3-layer forward, MI355X. CSR-based SpMM (built per-call), fused
// GEMM+bias+ReLU+LN-stats, fused LN-normalize+norm_src prescale.
// ---------------------------------------------------------------------------

__global__ __launch_bounds__(256) void degrees_k(const int* __restrict__ src,
                                                 const int* __restrict__ dst,
                                                 int* __restrict__ degO,
                                                 int* __restrict__ degI, int E) {
  int e = blockIdx.x * 256 + threadIdx.x;
  if (e < E) {
    atomicAdd(&degO[src[e]], 1);
    atomicAdd(&degI[dst[e]], 1);
  }
}

__global__ __launch_bounds__(256) void norm_k(const int* __restrict__ degO,
                                              const int* __restrict__ degI,
                                              float* __restrict__ ns,
                                              float* __restrict__ nd, int N) {
  int n = blockIdx.x * 256 + threadIdx.x;
  if (n < N) {
    int o = degO[n]; if (o < 1) o = 1;
    int i = degI[n]; if (i < 1) i = 1;
    ns[n] = rsqrtf((float)o);
    nd[n] = rsqrtf((float)i);
  }
}

// exclusive scan, phase 1: per-block (2048 elems) scan + block totals
__global__ __launch_bounds__(256) void scan1_k(const int* __restrict__ in,
                                               int* __restrict__ out,
                                               int* __restrict__ partials, int n) {
  __shared__ int sh[256];
  int t = threadIdx.x;
  int base = blockIdx.x * 2048 + t * 8;
  int v[8];
  int local = 0;
#pragma unroll
  for (int j = 0; j < 8; ++j) {
    int idx = base + j;
    v[j] = (idx < n) ? in[idx] : 0;
    local += v[j];
  }
  sh[t] = local;
  __syncthreads();
  int x = local;
  for (int off = 1; off < 256; off <<= 1) {
    int y = (t >= off) ? sh[t - off] : 0;
    __syncthreads();
    x += y;
    sh[t] = x;
    __syncthreads();
  }
  if (t == 255) partials[blockIdx.x] = x;
  int run = x - local;  // exclusive prefix for this thread's chunk
#pragma unroll
  for (int j = 0; j < 8; ++j) {
    int idx = base + j;
    if (idx < n) out[idx] = run;
    run += v[j];
  }
}

__global__ void scan2_k(int* partials, int nb) {
  if (threadIdx.x == 0 && blockIdx.x == 0) {
    int run = 0;
    for (int i = 0; i < nb; ++i) { int t = partials[i]; partials[i] = run; run += t; }
  }
}

__global__ __launch_bounds__(256) void scan3_k(int* __restrict__ row_start,
                                               int* __restrict__ cursor,
                                               const int* __restrict__ partials,
                                               int n, int total) {
  int i = blockIdx.x * 256 + threadIdx.x;
  if (i < n) {
    int val = row_start[i] + partials[i >> 11];
    row_start[i] = val;
    cursor[i] = val;
  }
  if (i == 0) row_start[n] = total;
}

__global__ __launch_bounds__(256) void fill_k(const int* __restrict__ src,
                                              const int* __restrict__ dst,
                                              int* __restrict__ cursor,
                                              int* __restrict__ edge_src, int E) {
  int e = blockIdx.x * 256 + threadIdx.x;
  if (e < E) {
    int d = dst[e];
    int pos = atomicAdd(&cursor[d], 1);
    edge_src[pos] = src[e];
  }
}

// A[n,f] = X[n,f] * ns[n]   (float4 per thread)
__global__ __launch_bounds__(256) void prescale_k(const float* __restrict__ X,
                                                  const float* __restrict__ ns,
                                                  float* __restrict__ A, int N) {
  size_t q = (size_t)blockIdx.x * 256 + threadIdx.x;
  if (q >= (size_t)N * 64) return;
  int row = (int)(q >> 6);
  float s = ns[row];
  float4 v = ((const float4*)X)[q];
  v.x *= s; v.y *= s; v.z *= s; v.w *= s;
  ((float4*)A)[q] = v;
}

// out[dst,:] = nd[dst] * sum_{e: dst} A[src_e,:]   one wave per row, F=256
__global__ __launch_bounds__(256) void spmm256_k(const float* __restrict__ A,
                                                 const int* __restrict__ rs,
                                                 const int* __restrict__ es,
                                                 const float* __restrict__ nd,
                                                 float* __restrict__ out, int N) {
  int w = (blockIdx.x * 256 + threadIdx.x) >> 6;
  int lane = threadIdx.x & 63;
  if (w >= N) return;
  int s = rs[w], e = rs[w + 1];
  float4 acc0 = make_float4(0.f, 0.f, 0.f, 0.f);
  float4 acc1 = make_float4(0.f, 0.f, 0.f, 0.f);
  int i = s;
  for (; i + 2 <= e; i += 2) {
    int s0 = es[i], s1 = es[i + 1];
    const float4 v0 = *(const float4*)(A + (size_t)s0 * 256 + lane * 4);
    const float4 v1 = *(const float4*)(A + (size_t)s1 * 256 + lane * 4);
    acc0.x += v0.x; acc0.y += v0.y; acc0.z += v0.z; acc0.w += v0.w;
    acc1.x += v1.x; acc1.y += v1.y; acc1.z += v1.z; acc1.w += v1.w;
  }
  if (i < e) {
    const float4 v0 = *(const float4*)(A + (size_t)es[i] * 256 + lane * 4);
    acc0.x += v0.x; acc0.y += v0.y; acc0.z += v0.z; acc0.w += v0.w;
  }
  float f = nd[w];
  float4 r;
  r.x = (acc0.x + acc1.x) * f;
  r.y = (acc0.y + acc1.y) * f;
  r.z = (acc0.z + acc1.z) * f;
  r.w = (acc0.w + acc1.w) * f;
  *(float4*)(out + (size_t)w * 256 + lane * 4) = r;
}

// out[dst,f] = nd[dst] * sum A[src,f] + b2[f]   one wave per row, F=64
__global__ __launch_bounds__(256) void spmm64_k(const float* __restrict__ G,
                                                const int* __restrict__ rs,
                                                const int* __restrict__ es,
                                                const float* __restrict__ nd,
                                                const float* __restrict__ b2,
                                                float* __restrict__ out, int N) {
  int w = (blockIdx.x * 256 + threadIdx.x) >> 6;
  int lane = threadIdx.x & 63;
  if (w >= N) return;
  int s = rs[w], e = rs[w + 1];
  float acc0 = 0.f, acc1 = 0.f;
  int i = s;
  for (; i + 2 <= e; i += 2) {
    acc0 += G[(size_t)es[i] * 64 + lane];
    acc1 += G[(size_t)es[i + 1] * 64 + lane];
  }
  if (i < e) acc0 += G[(size_t)es[i] * 64 + lane];
  out[(size_t)w * 64 + lane] = (acc0 + acc1) * nd[w] + b2[lane];
}

// C = Act[n_rows,256] @ W[256,n_cols]; EPI: += bias, ReLU, accumulate LN stats
template <bool EPI>
__global__ __launch_bounds__(256) void gemm_k(const float* __restrict__ Act,
                                              const float* __restrict__ W,
                                              const float* __restrict__ bias,
                                              float* __restrict__ Out,
                                              int n_rows, int n_cols,
                                              double* __restrict__ stats) {
  __shared__ float As[64][20];   // [m][k], padded stride 20 (80B, 16B-aligned)
  __shared__ float Bs[16][64];   // [k][n]
  __shared__ float red0[4], red1[4];
  const int tid = threadIdx.x;
  const int m0 = blockIdx.x * 64;
  const int n0 = blockIdx.y * 64;
  const int tx = tid & 15, ty = tid >> 4;
  const int arow = tid >> 2, akq = tid & 3;
  const int wrow = tid >> 4, wnq = tid & 15;
  const bool arow_ok = (m0 + arow) < n_rows;
  const float* actp = Act + (size_t)(m0 + arow) * 256 + akq * 4;
  const float* wp = W + (size_t)wrow * n_cols + n0 + wnq * 4;
  float acc[4][4] = {};
  for (int k0 = 0; k0 < 256; k0 += 16) {
    float4 av = make_float4(0.f, 0.f, 0.f, 0.f);
    if (arow_ok) av = *(const float4*)(actp + k0);
    float4 wv = *(const float4*)(wp + (size_t)k0 * n_cols);
    *(float4*)&As[arow][akq * 4] = av;
    *(float4*)&Bs[wrow][wnq * 4] = wv;
    __syncthreads();
#pragma unroll
    for (int k = 0; k < 16; k += 4) {
      float4 a4[4], b4[4];
#pragma unroll
      for (int i = 0; i < 4; ++i) a4[i] = *(const float4*)&As[ty * 4 + i][k];
#pragma unroll
      for (int kk = 0; kk < 4; ++kk) b4[kk] = *(const float4*)&Bs[k + kk][tx * 4];
      const float* af = (const float*)a4;  // af[i*4+kk]
      const float* bf = (const float*)b4;  // bf[kk*4+j]
#pragma unroll
      for (int kk = 0; kk < 4; ++kk)
#pragma unroll
        for (int i = 0; i < 4; ++i)
#pragma unroll
          for (int j = 0; j < 4; ++j)
            acc[i][j] += af[i * 4 + kk] * bf[kk * 4 + j];
    }
    __syncthreads();
  }
  float lsum = 0.f, lsq = 0.f;
#pragma unroll
  for (int i = 0; i < 4; ++i) {
    int row = m0 + ty * 4 + i;
    if (row < n_rows) {
#pragma unroll
      for (int j = 0; j < 4; ++j) {
        int col = n0 + tx * 4 + j;
        float v = acc[i][j];
        if (EPI) {
          v += bias[col];
          v = v > 0.f ? v : 0.f;
          lsum += v;
          lsq += v * v;
        }
        Out[(size_t)row * n_cols + col] = v;
      }
    }
  }
  if (EPI) {
#pragma unroll
    for (int off = 32; off > 0; off >>= 1) {
      lsum += __shfl_down(lsum, off, 64);
      lsq += __shfl_down(lsq, off, 64);
    }
    int lane = tid & 63, wv_ = tid >> 6;
    if (lane == 0) { red0[wv_] = lsum; red1[wv_] = lsq; }
    __syncthreads();
    if (tid == 0) {
      double s = 0.0, q = 0.0;
#pragma unroll
      for (int i = 0; i < 4; ++i) { s += (double)red0[i]; q += (double)red1[i]; }
      atomicAdd(stats, s);
      atomicAdd(stats + 1, q);
    }
  }
}

// A = (A - mu)*rsqrt(var+eps) * ns[row]   (LN normalize fused with prescale)
__global__ __launch_bounds__(256) void normp_k(float* __restrict__ A,
                                               const float* __restrict__ ns,
                                               const double* __restrict__ stats,
                                               double inv_count, int N) {
  size_t q = (size_t)blockIdx.x * 256 + threadIdx.x;
  if (q >= (size_t)N * 64) return;
  double mu = stats[0] * inv_count;
  double var = stats[1] * inv_count - mu * mu;
  float muf = (float)mu;
  float inv = (float)(1.0 / sqrt(var + 1e-5));
  int row = (int)(q >> 6);
  float sc = ns[row] * inv;
  float4 v = ((const float4*)A)[q];
  v.x = (v.x - muf) * sc;
  v.y = (v.y - muf) * sc;
  v.z = (v.z - muf) * sc;
  v.w = (v.w - muf) * sc;
  ((float4*)A)[q] = v;
}

extern "C" void kernel_launch(void* const* d_in, const int* in_sizes, int n_in,
                              void* d_out, int out_size, void* d_ws, size_t ws_size,
                              hipStream_t stream) {
  const float* features = (const float*)d_in[0];
  const int* src = (const int*)d_in[1];
  const int* dst = (const int*)d_in[2];
  const float* W0 = (const float*)d_in[3];
  const float* b0 = (const float*)d_in[4];
  const float* W1 = (const float*)d_in[5];
  const float* b1 = (const float*)d_in[6];
  const float* W2 = (const float*)d_in[7];
  const float* b2 = (const float*)d_in[8];
  float* out = (float*)d_out;

  const int N = in_sizes[0] / 256;
  const int E = in_sizes[1];

  char* ws = (char*)d_ws;
  size_t offA = 0;
  size_t offB = offA + (size_t)N * 256 * 4;
  size_t offEdge = offB + (size_t)N * 256 * 4;
  size_t offRow = offEdge + (size_t)E * 4;
  size_t offCur = offRow + ((size_t)N + 1) * 4;
  size_t offDegO = offCur + (size_t)N * 4;
  size_t offDegI = offDegO + (size_t)N * 4;
  size_t offNs = offDegI + (size_t)N * 4;
  size_t offNd = offNs + (size_t)N * 4;
  size_t offPart = offNd + (size_t)N * 4;
  size_t offStats = (offPart + 64 * 4 + 15) & ~(size_t)15;

  float* A = (float*)(ws + offA);
  float* B = (float*)(ws + offB);
  int* edge_src = (int*)(ws + offEdge);
  int* row_start = (int*)(ws + offRow);
  int* cursor = (int*)(ws + offCur);
  int* degO = (int*)(ws + offDegO);
  int* degI = (int*)(ws + offDegI);
  float* ns = (float*)(ws + offNs);
  float* nd = (float*)(ws + offNd);
  int* partials = (int*)(ws + offPart);
  double* stats = (double*)(ws + offStats);

  const int eb = (E + 255) / 256;
  const int nb = (N + 255) / 256;
  const int sb = (N + 2047) / 2048;
  const int qb = (N * 64 + 255) / 256;   // float4-quads over [N,256]
  const int wb = (N + 3) / 4;            // one wave per row
  const double inv_count = 1.0 / ((double)N * 256.0);

  // zero: degO+degI (contiguous) and 4 stat doubles
  hipMemsetAsync(degO, 0, (size_t)N * 8, stream);
  hipMemsetAsync(stats, 0, 4 * sizeof(double), stream);

  degrees_k<<<eb, 256, 0, stream>>>(src, dst, degO, degI, E);
  norm_k<<<nb, 256, 0, stream>>>(degO, degI, ns, nd, N);
  scan1_k<<<sb, 256, 0, stream>>>(degI, row_start, partials, N);
  scan2_k<<<1, 64, 0, stream>>>(partials, sb);
  scan3_k<<<nb, 256, 0, stream>>>(row_start, cursor, partials, N, E);
  fill_k<<<eb, 256, 0, stream>>>(src, dst, cursor, edge_src, E);

  // ---- layer 0 ----
  prescale_k<<<qb, 256, 0, stream>>>(features, ns, A, N);
  spmm256_k<<<wb, 256, 0, stream>>>(A, row_start, edge_src, nd, B, N);
  gemm_k<true><<<dim3((N + 63) / 64, 4), 256, 0, stream>>>(B, W0, b0, A, N, 256, stats);
  normp_k<<<qb, 256, 0, stream>>>(A, ns, stats, inv_count, N);

  // ---- layer 1 ----
  spmm256_k<<<wb, 256, 0, stream>>>(A, row_start, edge_src, nd, B, N);
  gemm_k<true><<<dim3((N + 63) / 64, 4), 256, 0, stream>>>(B, W1, b1, A, N, 256, stats + 2);
  normp_k<<<qb, 256, 0, stream>>>(A, ns, stats + 2, inv_count, N);

  // ---- layer 2: GEMM first (W commutes with aggregation), then F=64 SpMM ----
  gemm_k<false><<<dim3((N + 63) / 64, 1), 256, 0, stream>>>(A, W2, nullptr, B, N, 64, nullptr);
  spmm64_k<<<wb, 256, 0, stream>>>(B, row_start, edge_src, nd, b2, out, N);
}

// Round 8
// 2224.746 us; speedup vs baseline: 1.0092x; 1.0092x over previous
//
#include <hip/hip_runtime.h>

// ---------------------------------------------------------------------------
// GCN 3-layer forward, MI355X.
// R4 changes: (1) spmm: coalesced index prefetch + shfl broadcast + 4-deep
// independent gathers (was dependent index->gather chain, VALUBusy 11%).
// (2) GEMM: fp32-accurate bf16x3 MFMA (hi/lo split, 3 MFMAs) replacing
// fp32 vector GEMM (~310us each -> predict ~100us).
// ---------------------------------------------------------------------------

typedef __attribute__((ext_vector_type(8))) short short8v;   // 8 bf16 = 4 VGPR
typedef __attribute__((ext_vector_type(4))) float float4v;

static __device__ __forceinline__ unsigned short f2bf(float x) {
  unsigned int u = __float_as_uint(x);
  unsigned int r = (u + 0x7fffu + ((u >> 16) & 1u)) >> 16;   // RNE
  return (unsigned short)r;
}
static __device__ __forceinline__ float bf2f(unsigned short h) {
  return __uint_as_float((unsigned int)h << 16);
}

__global__ __launch_bounds__(256) void degrees_k(const int* __restrict__ src,
                                                 const int* __restrict__ dst,
                                                 int* __restrict__ degO,
                                                 int* __restrict__ degI, int E) {
  int e = blockIdx.x * 256 + threadIdx.x;
  if (e < E) {
    atomicAdd(&degO[src[e]], 1);
    atomicAdd(&degI[dst[e]], 1);
  }
}

__global__ __launch_bounds__(256) void norm_k(const int* __restrict__ degO,
                                              const int* __restrict__ degI,
                                              float* __restrict__ ns,
                                              float* __restrict__ nd, int N) {
  int n = blockIdx.x * 256 + threadIdx.x;
  if (n < N) {
    int o = degO[n]; if (o < 1) o = 1;
    int i = degI[n]; if (i < 1) i = 1;
    ns[n] = rsqrtf((float)o);
    nd[n] = rsqrtf((float)i);
  }
}

// exclusive scan, phase 1: per-block (2048 elems) scan + block totals
__global__ __launch_bounds__(256) void scan1_k(const int* __restrict__ in,
                                               int* __restrict__ out,
                                               int* __restrict__ partials, int n) {
  __shared__ int sh[256];
  int t = threadIdx.x;
  int base = blockIdx.x * 2048 + t * 8;
  int v[8];
  int local = 0;
#pragma unroll
  for (int j = 0; j < 8; ++j) {
    int idx = base + j;
    v[j] = (idx < n) ? in[idx] : 0;
    local += v[j];
  }
  sh[t] = local;
  __syncthreads();
  int x = local;
  for (int off = 1; off < 256; off <<= 1) {
    int y = (t >= off) ? sh[t - off] : 0;
    __syncthreads();
    x += y;
    sh[t] = x;
    __syncthreads();
  }
  if (t == 255) partials[blockIdx.x] = x;
  int run = x - local;
#pragma unroll
  for (int j = 0; j < 8; ++j) {
    int idx = base + j;
    if (idx < n) out[idx] = run;
    run += v[j];
  }
}

__global__ void scan2_k(int* partials, int nb) {
  if (threadIdx.x == 0 && blockIdx.x == 0) {
    int run = 0;
    for (int i = 0; i < nb; ++i) { int t = partials[i]; partials[i] = run; run += t; }
  }
}

__global__ __launch_bounds__(256) void scan3_k(int* __restrict__ row_start,
                                               int* __restrict__ cursor,
                                               const int* __restrict__ partials,
                                               int n, int total) {
  int i = blockIdx.x * 256 + threadIdx.x;
  if (i < n) {
    int val = row_start[i] + partials[i >> 11];
    row_start[i] = val;
    cursor[i] = val;
  }
  if (i == 0) row_start[n] = total;
}

__global__ __launch_bounds__(256) void fill_k(const int* __restrict__ src,
                                              const int* __restrict__ dst,
                                              int* __restrict__ cursor,
                                              int* __restrict__ edge_src, int E) {
  int e = blockIdx.x * 256 + threadIdx.x;
  if (e < E) {
    int d = dst[e];
    int pos = atomicAdd(&cursor[d], 1);
    edge_src[pos] = src[e];
  }
}

// W[k][c] f32 -> Whi[c][k], Wlo[c][k] bf16 planes (hi/lo split, transposed)
__global__ __launch_bounds__(256) void prepw_k(const float* __restrict__ W,
                                               unsigned short* __restrict__ Whi,
                                               unsigned short* __restrict__ Wlo,
                                               int K, int csh) {
  int C = 1 << csh;
  int idx = blockIdx.x * 256 + threadIdx.x;
  if (idx >= K * C) return;
  int k = idx >> csh, c = idx & (C - 1);
  float x = W[idx];
  unsigned short h = f2bf(x);
  Whi[c * K + k] = h;
  Wlo[c * K + k] = f2bf(x - bf2f(h));
}

// A[n,f] = X[n,f] * ns[n]
__global__ __launch_bounds__(256) void prescale_k(const float* __restrict__ X,
                                                  const float* __restrict__ ns,
                                                  float* __restrict__ A, int N) {
  size_t q = (size_t)blockIdx.x * 256 + threadIdx.x;
  if (q >= (size_t)N * 64) return;
  int row = (int)(q >> 6);
  float s = ns[row];
  float4 v = ((const float4*)X)[q];
  v.x *= s; v.y *= s; v.z *= s; v.w *= s;
  ((float4*)A)[q] = v;
}

// out[dst,:] = nd[dst] * sum_{e: dst} A[src_e,:]   one wave/row, F=256.
// Indices prefetched coalesced (64/load), shfl-broadcast, 4 gathers in flight.
__global__ __launch_bounds__(256) void spmm256_k(const float* __restrict__ A,
                                                 const int* __restrict__ rs,
                                                 const int* __restrict__ es,
                                                 const float* __restrict__ nd,
                                                 float* __restrict__ out, int N) {
  int w = (blockIdx.x * 256 + threadIdx.x) >> 6;
  int lane = threadIdx.x & 63;
  if (w >= N) return;
  const float4* A4 = (const float4*)A;
  int s = rs[w], e = rs[w + 1];
  float4 a0 = make_float4(0.f, 0.f, 0.f, 0.f);
  float4 a1 = a0, a2 = a0, a3 = a0;
  for (int base = s; base < e; base += 64) {
    int cnt = e - base; if (cnt > 64) cnt = 64;
    int nid = (base + lane < e) ? es[base + lane] : 0;
    int j = 0;
    for (; j + 4 <= cnt; j += 4) {
      int i0 = __shfl(nid, j, 64);
      int i1 = __shfl(nid, j + 1, 64);
      int i2 = __shfl(nid, j + 2, 64);
      int i3 = __shfl(nid, j + 3, 64);
      float4 v0 = A4[(size_t)i0 * 64 + lane];
      float4 v1 = A4[(size_t)i1 * 64 + lane];
      float4 v2 = A4[(size_t)i2 * 64 + lane];
      float4 v3 = A4[(size_t)i3 * 64 + lane];
      a0.x += v0.x; a0.y += v0.y; a0.z += v0.z; a0.w += v0.w;
      a1.x += v1.x; a1.y += v1.y; a1.z += v1.z; a1.w += v1.w;
      a2.x += v2.x; a2.y += v2.y; a2.z += v2.z; a2.w += v2.w;
      a3.x += v3.x; a3.y += v3.y; a3.z += v3.z; a3.w += v3.w;
    }
    for (; j < cnt; ++j) {
      int i0 = __shfl(nid, j, 64);
      float4 v0 = A4[(size_t)i0 * 64 + lane];
      a0.x += v0.x; a0.y += v0.y; a0.z += v0.z; a0.w += v0.w;
    }
  }
  float f = nd[w];
  float4 r;
  r.x = (a0.x + a1.x + a2.x + a3.x) * f;
  r.y = (a0.y + a1.y + a2.y + a3.y) * f;
  r.z = (a0.z + a1.z + a2.z + a3.z) * f;
  r.w = (a0.w + a1.w + a2.w + a3.w) * f;
  *(float4*)(out + (size_t)w * 256 + lane * 4) = r;
}

// out[dst,f] = nd[dst] * sum G[src,f] + b2[f]   one wave/row, F=64
__global__ __launch_bounds__(256) void spmm64_k(const float* __restrict__ G,
                                                const int* __restrict__ rs,
                                                const int* __restrict__ es,
                                                const float* __restrict__ nd,
                                                const float* __restrict__ b2,
                                                float* __restrict__ out, int N) {
  int w = (blockIdx.x * 256 + threadIdx.x) >> 6;
  int lane = threadIdx.x & 63;
  if (w >= N) return;
  int s = rs[w], e = rs[w + 1];
  float a0 = 0.f, a1 = 0.f, a2 = 0.f, a3 = 0.f;
  for (int base = s; base < e; base += 64) {
    int cnt = e - base; if (cnt > 64) cnt = 64;
    int nid = (base + lane < e) ? es[base + lane] : 0;
    int j = 0;
    for (; j + 4 <= cnt; j += 4) {
      int i0 = __shfl(nid, j, 64);
      int i1 = __shfl(nid, j + 1, 64);
      int i2 = __shfl(nid, j + 2, 64);
      int i3 = __shfl(nid, j + 3, 64);
      a0 += G[(size_t)i0 * 64 + lane];
      a1 += G[(size_t)i1 * 64 + lane];
      a2 += G[(size_t)i2 * 64 + lane];
      a3 += G[(size_t)i3 * 64 + lane];
    }
    for (; j < cnt; ++j) {
      int i0 = __shfl(nid, j, 64);
      a0 += G[(size_t)i0 * 64 + lane];
    }
  }
  out[(size_t)w * 64 + lane] = (a0 + a1 + a2 + a3) * nd[w] + b2[lane];
}

// C[nr,nc] = Act[nr,256] @ W[256,nc] via bf16x3 MFMA (fp32-accurate).
// Wt given as hi/lo bf16 planes [c][k]. EPI: +bias, ReLU, LN stats.
// Block 256 thr = 4 waves; tile 64x64; wave = 16-row strip x 64 cols.
template <bool EPI>
__global__ __launch_bounds__(256) void gemm_k(const float* __restrict__ Act,
                                              const unsigned short* __restrict__ Whi,
                                              const unsigned short* __restrict__ Wlo,
                                              const float* __restrict__ bias,
                                              float* __restrict__ Out,
                                              int n_rows, int n_cols,
                                              double* __restrict__ stats) {
  __shared__ float As[64][36];            // 64 rows x 32 k f32 (pad 4: 2-way free)
  __shared__ unsigned short Hs[64][40];   // Wt tile [col][k] hi (pad 8)
  __shared__ unsigned short Ls[64][40];   // Wt tile [col][k] lo
  __shared__ float red0[4], red1[4];
  const int tid = threadIdx.x;
  const int wv = tid >> 6, lane = tid & 63;
  const int r16 = lane & 15, kg = lane >> 4;       // frag row/col, k-group
  const int m0 = blockIdx.x * 64, n0 = blockIdx.y * 64;
  const int srow = tid >> 2;                        // staging row 0..63
  const int sk = (tid & 3) * 8;                     // staging k {0,8,16,24}
  const bool srow_ok = (m0 + srow) < n_rows;
  const float* ap = Act + (size_t)(m0 + srow) * 256 + sk;
  const unsigned short* hp = Whi + (size_t)(n0 + srow) * 256 + sk;
  const unsigned short* lp = Wlo + (size_t)(n0 + srow) * 256 + sk;
  float4v acc[4] = {};
  for (int k0 = 0; k0 < 256; k0 += 32) {
    float4 s0 = make_float4(0.f, 0.f, 0.f, 0.f), s1 = s0;
    if (srow_ok) {
      s0 = *(const float4*)(ap + k0);
      s1 = *(const float4*)(ap + k0 + 4);
    }
    uint4 h4 = *(const uint4*)(hp + k0);
    uint4 l4 = *(const uint4*)(lp + k0);
    *(float4*)&As[srow][sk] = s0;
    *(float4*)&As[srow][sk + 4] = s1;
    *(uint4*)&Hs[srow][sk] = h4;
    *(uint4*)&Ls[srow][sk] = l4;
    __syncthreads();
    // A fragment: row = 16*wv + r16, k = 8*kg + i  -> hi/lo split in regs
    const float* arp = &As[16 * wv + r16][8 * kg];
    float4 av0 = *(const float4*)(arp);
    float4 av1 = *(const float4*)(arp + 4);
    float ax[8] = {av0.x, av0.y, av0.z, av0.w, av1.x, av1.y, av1.z, av1.w};
    short8v ahi, alo;
#pragma unroll
    for (int i = 0; i < 8; ++i) {
      unsigned short h = f2bf(ax[i]);
      ahi[i] = (short)h;
      alo[i] = (short)f2bf(ax[i] - bf2f(h));
    }
#pragma unroll
    for (int t = 0; t < 4; ++t) {
      short8v bhi = *(const short8v*)&Hs[16 * t + r16][8 * kg];
      short8v blo = *(const short8v*)&Ls[16 * t + r16][8 * kg];
      acc[t] = __builtin_amdgcn_mfma_f32_16x16x32_bf16(ahi, bhi, acc[t], 0, 0, 0);
      acc[t] = __builtin_amdgcn_mfma_f32_16x16x32_bf16(ahi, blo, acc[t], 0, 0, 0);
      acc[t] = __builtin_amdgcn_mfma_f32_16x16x32_bf16(alo, bhi, acc[t], 0, 0, 0);
    }
    __syncthreads();
  }
  // D layout: row = 16*wv + 4*kg + j, col = n0 + 16*t + r16
  float lsum = 0.f, lsq = 0.f;
#pragma unroll
  for (int t = 0; t < 4; ++t) {
    int col = n0 + 16 * t + r16;
    float b = EPI ? bias[col] : 0.f;
#pragma unroll
    for (int j = 0; j < 4; ++j) {
      int row = m0 + 16 * wv + 4 * kg + j;
      if (row < n_rows) {
        float v = acc[t][j];
        if (EPI) {
          v += b;
          v = v > 0.f ? v : 0.f;
          lsum += v;
          lsq += v * v;
        }
        Out[(size_t)row * n_cols + col] = v;
      }
    }
  }
  if (EPI) {
#pragma unroll
    for (int off = 32; off > 0; off >>= 1) {
      lsum += __shfl_down(lsum, off, 64);
      lsq += __shfl_down(lsq, off, 64);
    }
    if (lane == 0) { red0[wv] = lsum; red1[wv] = lsq; }
    __syncthreads();
    if (tid == 0) {
      double s = 0.0, q = 0.0;
#pragma unroll
      for (int i = 0; i < 4; ++i) { s += (double)red0[i]; q += (double)red1[i]; }
      atomicAdd(stats, s);
      atomicAdd(stats + 1, q);
    }
  }
}

// A = (A - mu)*rsqrt(var+eps) * ns[row]
__global__ __launch_bounds__(256) void normp_k(float* __restrict__ A,
                                               const float* __restrict__ ns,
                                               const double* __restrict__ stats,
                                               double inv_count, int N) {
  size_t q = (size_t)blockIdx.x * 256 + threadIdx.x;
  if (q >= (size_t)N * 64) return;
  double mu = stats[0] * inv_count;
  double var = stats[1] * inv_count - mu * mu;
  float muf = (float)mu;
  float inv = (float)(1.0 / sqrt(var + 1e-5));
  int row = (int)(q >> 6);
  float sc = ns[row] * inv;
  float4 v = ((const float4*)A)[q];
  v.x = (v.x - muf) * sc;
  v.y = (v.y - muf) * sc;
  v.z = (v.z - muf) * sc;
  v.w = (v.w - muf) * sc;
  ((float4*)A)[q] = v;
}

extern "C" void kernel_launch(void* const* d_in, const int* in_sizes, int n_in,
                              void* d_out, int out_size, void* d_ws, size_t ws_size,
                              hipStream_t stream) {
  const float* features = (const float*)d_in[0];
  const int* src = (const int*)d_in[1];
  const int* dst = (const int*)d_in[2];
  const float* W0 = (const float*)d_in[3];
  const float* b0 = (const float*)d_in[4];
  const float* W1 = (const float*)d_in[5];
  const float* b1 = (const float*)d_in[6];
  const float* W2 = (const float*)d_in[7];
  const float* b2 = (const float*)d_in[8];
  float* out = (float*)d_out;

  const int N = in_sizes[0] / 256;
  const int E = in_sizes[1];

  char* ws = (char*)d_ws;
  size_t offA = 0;
  size_t offB = offA + (size_t)N * 256 * 4;
  size_t offEdge = offB + (size_t)N * 256 * 4;
  size_t offRow = offEdge + (size_t)E * 4;
  size_t offCur = offRow + ((size_t)N + 1) * 4;
  size_t offDegO = offCur + (size_t)N * 4;
  size_t offDegI = offDegO + (size_t)N * 4;
  size_t offNs = offDegI + (size_t)N * 4;
  size_t offNd = offNs + (size_t)N * 4;
  size_t offPart = offNd + (size_t)N * 4;
  size_t offStats = (offPart + 64 * 4 + 15) & ~(size_t)15;
  size_t offW = (offStats + 4 * sizeof(double) + 15) & ~(size_t)15;
  size_t offWh0 = offW;
  size_t offWl0 = offWh0 + 256 * 256 * 2;
  size_t offWh1 = offWl0 + 256 * 256 * 2;
  size_t offWl1 = offWh1 + 256 * 256 * 2;
  size_t offWh2 = offWl1 + 256 * 256 * 2;
  size_t offWl2 = offWh2 + 256 * 64 * 2;

  float* A = (float*)(ws + offA);
  float* B = (float*)(ws + offB);
  int* edge_src = (int*)(ws + offEdge);
  int* row_start = (int*)(ws + offRow);
  int* cursor = (int*)(ws + offCur);
  int* degO = (int*)(ws + offDegO);
  int* degI = (int*)(ws + offDegI);
  float* ns = (float*)(ws + offNs);
  float* nd = (float*)(ws + offNd);
  int* partials = (int*)(ws + offPart);
  double* stats = (double*)(ws + offStats);
  unsigned short* Wh0 = (unsigned short*)(ws + offWh0);
  unsigned short* Wl0 = (unsigned short*)(ws + offWl0);
  unsigned short* Wh1 = (unsigned short*)(ws + offWh1);
  unsigned short* Wl1 = (unsigned short*)(ws + offWl1);
  unsigned short* Wh2 = (unsigned short*)(ws + offWh2);
  unsigned short* Wl2 = (unsigned short*)(ws + offWl2);

  const int eb = (E + 255) / 256;
  const int nb = (N + 255) / 256;
  const int sb = (N + 2047) / 2048;
  const int qb = (N * 64 + 255) / 256;
  const int wb = (N + 3) / 4;
  const int gx = (N + 63) / 64;
  const double inv_count = 1.0 / ((double)N * 256.0);

  hipMemsetAsync(degO, 0, (size_t)N * 8, stream);
  hipMemsetAsync(stats, 0, 4 * sizeof(double), stream);

  // W hi/lo split + transpose (once per call)
  prepw_k<<<256, 256, 0, stream>>>(W0, Wh0, Wl0, 256, 8);
  prepw_k<<<256, 256, 0, stream>>>(W1, Wh1, Wl1, 256, 8);
  prepw_k<<<64, 256, 0, stream>>>(W2, Wh2, Wl2, 256, 6);

  degrees_k<<<eb, 256, 0, stream>>>(src, dst, degO, degI, E);
  norm_k<<<nb, 256, 0, stream>>>(degO, degI, ns, nd, N);
  scan1_k<<<sb, 256, 0, stream>>>(degI, row_start, partials, N);
  scan2_k<<<1, 64, 0, stream>>>(partials, sb);
  scan3_k<<<nb, 256, 0, stream>>>(row_start, cursor, partials, N, E);
  fill_k<<<eb, 256, 0, stream>>>(src, dst, cursor, edge_src, E);

  // ---- layer 0 ----
  prescale_k<<<qb, 256, 0, stream>>>(features, ns, A, N);
  spmm256_k<<<wb, 256, 0, stream>>>(A, row_start, edge_src, nd, B, N);
  gemm_k<true><<<dim3(gx, 4), 256, 0, stream>>>(B, Wh0, Wl0, b0, A, N, 256, stats);
  normp_k<<<qb, 256, 0, stream>>>(A, ns, stats, inv_count, N);

  // ---- layer 1 ----
  spmm256_k<<<wb, 256, 0, stream>>>(A, row_start, edge_src, nd, B, N);
  gemm_k<true><<<dim3(gx, 4), 256, 0, stream>>>(B, Wh1, Wl1, b1, A, N, 256, stats + 2);
  normp_k<<<qb, 256, 0, stream>>>(A, ns, stats + 2, inv_count, N);

  // ---- layer 2: GEMM first (W commutes with aggregation), then F=64 SpMM ----
  gemm_k<false><<<dim3(gx, 1), 256, 0, stream>>>(A, Wh2, Wl2, nullptr, B, N, 64, nullptr);
  spmm64_k<<<wb, 256, 0, stream>>>(B, row_start, edge_src, nd, b2, out, N);
}

// Round 10
// 1683.032 us; speedup vs baseline: 1.3340x; 1.3219x over previous
//
#include <hip/hip_runtime.h>
#include <hip/hip_fp16.h>

// ---------------------------------------------------------------------------
// GCN 3-layer forward, MI355X.
// R8: fp16 gather pipeline (halve SpMM bytes), SpMM emits bf16 hi/lo planes
// (exact split; GEMM consumes directly - no in-kernel conversion),
// ping-pong R1/R2 aliasing keeps ws at proven ~220MB.
// ---------------------------------------------------------------------------

typedef __attribute__((ext_vector_type(8))) short short8v;   // 8 bf16 = 4 VGPR
typedef __attribute__((ext_vector_type(4))) float float4v;

struct alignas(8) h4_t { __half2 lo, hi; };   // 4 fp16 = 8B

static __device__ __forceinline__ unsigned short f2bf(float x) {
  unsigned int u = __float_as_uint(x);
  unsigned int r = (u + 0x7fffu + ((u >> 16) & 1u)) >> 16;   // RNE
  return (unsigned short)r;
}
static __device__ __forceinline__ float bf2f(unsigned short h) {
  return __uint_as_float((unsigned int)h << 16);
}
static __device__ __forceinline__ unsigned int f2h2(float a, float b) {
  __half2 h = __floats2half2_rn(a, b);
  return *(unsigned int*)&h;
}
static __device__ __forceinline__ unsigned int bfpack(float a, float b) {
  return (unsigned int)f2bf(a) | ((unsigned int)f2bf(b) << 16);
}

__global__ __launch_bounds__(256) void degrees_k(const int* __restrict__ src,
                                                 const int* __restrict__ dst,
                                                 int* __restrict__ degO,
                                                 int* __restrict__ degI, int E) {
  int e = blockIdx.x * 256 + threadIdx.x;
  if (e < E) {
    atomicAdd(&degO[src[e]], 1);
    atomicAdd(&degI[dst[e]], 1);
  }
}

__global__ __launch_bounds__(256) void norm_k(const int* __restrict__ degO,
                                              const int* __restrict__ degI,
                                              float* __restrict__ ns,
                                              float* __restrict__ nd, int N) {
  int n = blockIdx.x * 256 + threadIdx.x;
  if (n < N) {
    int o = degO[n]; if (o < 1) o = 1;
    int i = degI[n]; if (i < 1) i = 1;
    ns[n] = rsqrtf((float)o);
    nd[n] = rsqrtf((float)i);
  }
}

__global__ __launch_bounds__(256) void scan1_k(const int* __restrict__ in,
                                               int* __restrict__ out,
                                               int* __restrict__ partials, int n) {
  __shared__ int sh[256];
  int t = threadIdx.x;
  int base = blockIdx.x * 2048 + t * 8;
  int v[8];
  int local = 0;
#pragma unroll
  for (int j = 0; j < 8; ++j) {
    int idx = base + j;
    v[j] = (idx < n) ? in[idx] : 0;
    local += v[j];
  }
  sh[t] = local;
  __syncthreads();
  int x = local;
  for (int off = 1; off < 256; off <<= 1) {
    int y = (t >= off) ? sh[t - off] : 0;
    __syncthreads();
    x += y;
    sh[t] = x;
    __syncthreads();
  }
  if (t == 255) partials[blockIdx.x] = x;
  int run = x - local;
#pragma unroll
  for (int j = 0; j < 8; ++j) {
    int idx = base + j;
    if (idx < n) out[idx] = run;
    run += v[j];
  }
}

__global__ void scan2_k(int* partials, int nb) {
  if (threadIdx.x == 0 && blockIdx.x == 0) {
    int run = 0;
    for (int i = 0; i < nb; ++i) { int t = partials[i]; partials[i] = run; run += t; }
  }
}

__global__ __launch_bounds__(256) void scan3_k(int* __restrict__ row_start,
                                               int* __restrict__ cursor,
                                               const int* __restrict__ partials,
                                               int n, int total) {
  int i = blockIdx.x * 256 + threadIdx.x;
  if (i < n) {
    int val = row_start[i] + partials[i >> 11];
    row_start[i] = val;
    cursor[i] = val;
  }
  if (i == 0) row_start[n] = total;
}

__global__ __launch_bounds__(256) void fill_k(const int* __restrict__ src,
                                              const int* __restrict__ dst,
                                              int* __restrict__ cursor,
                                              int* __restrict__ edge_src, int E) {
  int e = blockIdx.x * 256 + threadIdx.x;
  if (e < E) {
    int d = dst[e];
    int pos = atomicAdd(&cursor[d], 1);
    edge_src[pos] = src[e];
  }
}

// W[k][c] f32 -> Whi[c][k], Wlo[c][k] bf16 planes
__global__ __launch_bounds__(256) void prepw_k(const float* __restrict__ W,
                                               unsigned short* __restrict__ Whi,
                                               unsigned short* __restrict__ Wlo,
                                               int K, int csh) {
  int C = 1 << csh;
  int idx = blockIdx.x * 256 + threadIdx.x;
  if (idx >= K * C) return;
  int k = idx >> csh, c = idx & (C - 1);
  float x = W[idx];
  unsigned short h = f2bf(x);
  Whi[c * K + k] = h;
  Wlo[c * K + k] = f2bf(x - bf2f(h));
}

// Ah[n,f] = fp16( X[n,f] * ns[n] )   8 elems/thread
__global__ __launch_bounds__(256) void prescale_h_k(const float* __restrict__ X,
                                                    const float* __restrict__ ns,
                                                    __half* __restrict__ Ah, int N) {
  size_t q = (size_t)blockIdx.x * 256 + threadIdx.x;
  if (q >= (size_t)N * 32) return;
  int row = (int)(q >> 5);
  float s = ns[row];
  float4 v0 = ((const float4*)X)[q * 2];
  float4 v1 = ((const float4*)X)[q * 2 + 1];
  uint4 o;
  o.x = f2h2(v0.x * s, v0.y * s);
  o.y = f2h2(v0.z * s, v0.w * s);
  o.z = f2h2(v1.x * s, v1.y * s);
  o.w = f2h2(v1.z * s, v1.w * s);
  ((uint4*)Ah)[q] = o;
}

// normp -> fp16: Ah = fp16( (A - mu)*inv*ns[row] )
__global__ __launch_bounds__(256) void normp_h_k(const float* __restrict__ A,
                                                 const float* __restrict__ ns,
                                                 const double* __restrict__ stats,
                                                 double inv_count,
                                                 __half* __restrict__ Ah, int N) {
  size_t q = (size_t)blockIdx.x * 256 + threadIdx.x;
  if (q >= (size_t)N * 32) return;
  double mu = stats[0] * inv_count;
  double var = stats[1] * inv_count - mu * mu;
  float muf = (float)mu;
  float inv = (float)(1.0 / sqrt(var + 1e-5));
  int row = (int)(q >> 5);
  float sc = ns[row] * inv;
  float4 v0 = ((const float4*)A)[q * 2];
  float4 v1 = ((const float4*)A)[q * 2 + 1];
  uint4 o;
  o.x = f2h2((v0.x - muf) * sc, (v0.y - muf) * sc);
  o.y = f2h2((v0.z - muf) * sc, (v0.w - muf) * sc);
  o.z = f2h2((v1.x - muf) * sc, (v1.y - muf) * sc);
  o.w = f2h2((v1.z - muf) * sc, (v1.w - muf) * sc);
  ((uint4*)Ah)[q] = o;
}

// normp -> bf16 hi/lo planes (exact split of the f32 result)
__global__ __launch_bounds__(256) void normp_p_k(const float* __restrict__ A,
                                                 const float* __restrict__ ns,
                                                 const double* __restrict__ stats,
                                                 double inv_count,
                                                 unsigned short* __restrict__ Phi,
                                                 unsigned short* __restrict__ Plo,
                                                 int N) {
  size_t q = (size_t)blockIdx.x * 256 + threadIdx.x;
  if (q >= (size_t)N * 32) return;
  double mu = stats[0] * inv_count;
  double var = stats[1] * inv_count - mu * mu;
  float muf = (float)mu;
  float inv = (float)(1.0 / sqrt(var + 1e-5));
  int row = (int)(q >> 5);
  float sc = ns[row] * inv;
  float x[8];
  float4 v0 = ((const float4*)A)[q * 2];
  float4 v1 = ((const float4*)A)[q * 2 + 1];
  x[0] = (v0.x - muf) * sc; x[1] = (v0.y - muf) * sc;
  x[2] = (v0.z - muf) * sc; x[3] = (v0.w - muf) * sc;
  x[4] = (v1.x - muf) * sc; x[5] = (v1.y - muf) * sc;
  x[6] = (v1.z - muf) * sc; x[7] = (v1.w - muf) * sc;
  uint4 hv, lv;
  unsigned short h;
  float r;
#define SPLIT2(dst_h, dst_l, a, b)                    \
  { unsigned short ha = f2bf(a); float ra = (a) - bf2f(ha);  \
    unsigned short hb = f2bf(b); float rb = (b) - bf2f(hb);  \
    dst_h = (unsigned int)ha | ((unsigned int)hb << 16);     \
    dst_l = (unsigned int)f2bf(ra) | ((unsigned int)f2bf(rb) << 16); }
  SPLIT2(hv.x, lv.x, x[0], x[1]);
  SPLIT2(hv.y, lv.y, x[2], x[3]);
  SPLIT2(hv.z, lv.z, x[4], x[5]);
  SPLIT2(hv.w, lv.w, x[6], x[7]);
#undef SPLIT2
  (void)h; (void)r;
  ((uint4*)Phi)[q] = hv;
  ((uint4*)Plo)[q] = lv;
}

// spmm fp16 gather F=256: Bhi/Blo[dst,:] = split( nd[dst] * sum Ah[src,:] )
__global__ __launch_bounds__(256) void spmm256_h_k(const __half* __restrict__ Ah,
                                                   const int* __restrict__ rs,
                                                   const int* __restrict__ es,
                                                   const float* __restrict__ nd,
                                                   unsigned short* __restrict__ Bhi,
                                                   unsigned short* __restrict__ Blo,
                                                   int N) {
  int w = (blockIdx.x * 256 + threadIdx.x) >> 6;
  int lane = threadIdx.x & 63;
  if (w >= N) return;
  int s = rs[w], e = rs[w + 1];
  float4 a0 = make_float4(0.f, 0.f, 0.f, 0.f);
  float4 a1 = a0, a2 = a0, a3 = a0;
  int i = s;
  for (; i + 4 <= e; i += 4) {
    int i0 = es[i], i1 = es[i + 1], i2 = es[i + 2], i3 = es[i + 3];
    h4_t v0 = ((const h4_t*)(Ah + (size_t)i0 * 256))[lane];
    h4_t v1 = ((const h4_t*)(Ah + (size_t)i1 * 256))[lane];
    h4_t v2 = ((const h4_t*)(Ah + (size_t)i2 * 256))[lane];
    h4_t v3 = ((const h4_t*)(Ah + (size_t)i3 * 256))[lane];
    float2 f;
    f = __half22float2(v0.lo); a0.x += f.x; a0.y += f.y;
    f = __half22float2(v0.hi); a0.z += f.x; a0.w += f.y;
    f = __half22float2(v1.lo); a1.x += f.x; a1.y += f.y;
    f = __half22float2(v1.hi); a1.z += f.x; a1.w += f.y;
    f = __half22float2(v2.lo); a2.x += f.x; a2.y += f.y;
    f = __half22float2(v2.hi); a2.z += f.x; a2.w += f.y;
    f = __half22float2(v3.lo); a3.x += f.x; a3.y += f.y;
    f = __half22float2(v3.hi); a3.z += f.x; a3.w += f.y;
  }
  for (; i < e; ++i) {
    h4_t v0 = ((const h4_t*)(Ah + (size_t)es[i] * 256))[lane];
    float2 f;
    f = __half22float2(v0.lo); a0.x += f.x; a0.y += f.y;
    f = __half22float2(v0.hi); a0.z += f.x; a0.w += f.y;
  }
  float fd = nd[w];
  float r0 = (a0.x + a1.x + a2.x + a3.x) * fd;
  float r1 = (a0.y + a1.y + a2.y + a3.y) * fd;
  float r2 = (a0.z + a1.z + a2.z + a3.z) * fd;
  float r3 = (a0.w + a1.w + a2.w + a3.w) * fd;
  ushort4 rh, rl;
  rh.x = f2bf(r0); rl.x = f2bf(r0 - bf2f(rh.x));
  rh.y = f2bf(r1); rl.y = f2bf(r1 - bf2f(rh.y));
  rh.z = f2bf(r2); rl.z = f2bf(r2 - bf2f(rh.z));
  rh.w = f2bf(r3); rl.w = f2bf(r3 - bf2f(rh.w));
  *(ushort4*)(Bhi + (size_t)w * 256 + lane * 4) = rh;
  *(ushort4*)(Blo + (size_t)w * 256 + lane * 4) = rl;
}

// spmm fp16 gather F=64: out[dst,f] = nd[dst]*sum Gh[src,f] + b2[f]  (f32 out)
__global__ __launch_bounds__(256) void spmm64_h_k(const __half* __restrict__ Gh,
                                                  const int* __restrict__ rs,
                                                  const int* __restrict__ es,
                                                  const float* __restrict__ nd,
                                                  const float* __restrict__ b2,
                                                  float* __restrict__ out, int N) {
  int w = (blockIdx.x * 256 + threadIdx.x) >> 6;
  int lane = threadIdx.x & 63;
  if (w >= N) return;
  int s = rs[w], e = rs[w + 1];
  float a0 = 0.f, a1 = 0.f, a2 = 0.f, a3 = 0.f;
  float a4 = 0.f, a5 = 0.f, a6 = 0.f, a7 = 0.f;
  int i = s;
  for (; i + 8 <= e; i += 8) {
    a0 += __half2float(Gh[(size_t)es[i] * 64 + lane]);
    a1 += __half2float(Gh[(size_t)es[i + 1] * 64 + lane]);
    a2 += __half2float(Gh[(size_t)es[i + 2] * 64 + lane]);
    a3 += __half2float(Gh[(size_t)es[i + 3] * 64 + lane]);
    a4 += __half2float(Gh[(size_t)es[i + 4] * 64 + lane]);
    a5 += __half2float(Gh[(size_t)es[i + 5] * 64 + lane]);
    a6 += __half2float(Gh[(size_t)es[i + 6] * 64 + lane]);
    a7 += __half2float(Gh[(size_t)es[i + 7] * 64 + lane]);
  }
  for (; i < e; ++i) a0 += __half2float(Gh[(size_t)es[i] * 64 + lane]);
  float t = ((a0 + a1) + (a2 + a3)) + ((a4 + a5) + (a6 + a7));
  out[(size_t)w * 64 + lane] = t * nd[w] + b2[lane];
}

// C[nr,nc] = Act @ W via bf16x3 MFMA; Act given as bf16 hi/lo planes [row][k].
// EPI: +bias, ReLU, LN stats.  OUTH: write fp16 (layer 2).
template <bool EPI, bool OUTH>
__global__ __launch_bounds__(256) void gemm_k(const unsigned short* __restrict__ Ahi,
                                              const unsigned short* __restrict__ Alo,
                                              const unsigned short* __restrict__ Whi,
                                              const unsigned short* __restrict__ Wlo,
                                              const float* __restrict__ bias,
                                              float* __restrict__ Out,
                                              __half* __restrict__ OutH,
                                              int n_rows, int n_cols,
                                              double* __restrict__ stats) {
  __shared__ unsigned short Ahs[64][40];  // Act tile hi [row][k], pad 8
  __shared__ unsigned short Als[64][40];  // Act tile lo
  __shared__ unsigned short Hs[64][40];   // W tile hi  [col][k]
  __shared__ unsigned short Ls[64][40];   // W tile lo
  __shared__ float red0[4], red1[4];
  const int tid = threadIdx.x;
  const int wv = tid >> 6, lane = tid & 63;
  const int r16 = lane & 15, kg = lane >> 4;
  const int m0 = blockIdx.x * 64, n0 = blockIdx.y * 64;
  const int srow = tid >> 2;
  const int sk = (tid & 3) * 8;
  const bool srow_ok = (m0 + srow) < n_rows;
  const unsigned short* ahp = Ahi + (size_t)(m0 + srow) * 256 + sk;
  const unsigned short* alp = Alo + (size_t)(m0 + srow) * 256 + sk;
  const unsigned short* hp = Whi + (size_t)(n0 + srow) * 256 + sk;
  const unsigned short* lp = Wlo + (size_t)(n0 + srow) * 256 + sk;
  float4v acc[4] = {};
  for (int k0 = 0; k0 < 256; k0 += 32) {
    uint4 za = make_uint4(0, 0, 0, 0), zl = za;
    if (srow_ok) {
      za = *(const uint4*)(ahp + k0);
      zl = *(const uint4*)(alp + k0);
    }
    uint4 h4 = *(const uint4*)(hp + k0);
    uint4 l4 = *(const uint4*)(lp + k0);
    *(uint4*)&Ahs[srow][sk] = za;
    *(uint4*)&Als[srow][sk] = zl;
    *(uint4*)&Hs[srow][sk] = h4;
    *(uint4*)&Ls[srow][sk] = l4;
    __syncthreads();
    short8v ahi = *(const short8v*)&Ahs[16 * wv + r16][8 * kg];
    short8v alo = *(const short8v*)&Als[16 * wv + r16][8 * kg];
#pragma unroll
    for (int t = 0; t < 4; ++t) {
      short8v bhi = *(const short8v*)&Hs[16 * t + r16][8 * kg];
      short8v blo = *(const short8v*)&Ls[16 * t + r16][8 * kg];
      acc[t] = __builtin_amdgcn_mfma_f32_16x16x32_bf16(ahi, bhi, acc[t], 0, 0, 0);
      acc[t] = __builtin_amdgcn_mfma_f32_16x16x32_bf16(ahi, blo, acc[t], 0, 0, 0);
      acc[t] = __builtin_amdgcn_mfma_f32_16x16x32_bf16(alo, bhi, acc[t], 0, 0, 0);
    }
    __syncthreads();
  }
  // D layout: row = m0 + 16*wv + 4*kg + j, col = n0 + 16*t + r16
  float lsum = 0.f, lsq = 0.f;
#pragma unroll
  for (int t = 0; t < 4; ++t) {
    int col = n0 + 16 * t + r16;
    float b = EPI ? bias[col] : 0.f;
#pragma unroll
    for (int j = 0; j < 4; ++j) {
      int row = m0 + 16 * wv + 4 * kg + j;
      if (row < n_rows) {
        float v = acc[t][j];
        if (EPI) {
          v += b;
          v = v > 0.f ? v : 0.f;
          lsum += v;
          lsq += v * v;
        }
        if (OUTH) OutH[(size_t)row * n_cols + col] = __float2half(v);
        else      Out[(size_t)row * n_cols + col] = v;
      }
    }
  }
  if (EPI) {
#pragma unroll
    for (int off = 32; off > 0; off >>= 1) {
      lsum += __shfl_down(lsum, off, 64);
      lsq += __shfl_down(lsq, off, 64);
    }
    if (lane == 0) { red0[wv] = lsum; red1[wv] = lsq; }
    __syncthreads();
    if (tid == 0) {
      double s = 0.0, q = 0.0;
#pragma unroll
      for (int i = 0; i < 4; ++i) { s += (double)red0[i]; q += (double)red1[i]; }
      atomicAdd(stats, s);
      atomicAdd(stats + 1, q);
    }
  }
}

extern "C" void kernel_launch(void* const* d_in, const int* in_sizes, int n_in,
                              void* d_out, int out_size, void* d_ws, size_t ws_size,
                              hipStream_t stream) {
  const float* features = (const float*)d_in[0];
  const int* src = (const int*)d_in[1];
  const int* dst = (const int*)d_in[2];
  const float* W0 = (const float*)d_in[3];
  const float* b0 = (const float*)d_in[4];
  const float* W1 = (const float*)d_in[5];
  const float* b1 = (const float*)d_in[6];
  const float* W2 = (const float*)d_in[7];
  const float* b2 = (const float*)d_in[8];
  float* out = (float*)d_out;

  const int N = in_sizes[0] / 256;
  const int E = in_sizes[1];

  char* ws = (char*)d_ws;
  const size_t szPlane = (size_t)N * 256 * 2;   // 51.2MB
  const size_t szR = 2 * szPlane;               // 102.4MB
  char* R1 = ws;
  char* R2 = ws + szR;
  size_t offEdge = 2 * szR;
  size_t offRow = offEdge + (size_t)E * 4;
  size_t offCur = offRow + ((size_t)N + 1) * 4;
  size_t offDegO = offCur + (size_t)N * 4;
  size_t offDegI = offDegO + (size_t)N * 4;
  size_t offNs = offDegI + (size_t)N * 4;
  size_t offNd = offNs + (size_t)N * 4;
  size_t offPart = offNd + (size_t)N * 4;
  size_t offStats = (offPart + 64 * 4 + 15) & ~(size_t)15;
  size_t offW = (offStats + 4 * sizeof(double) + 15) & ~(size_t)15;
  size_t offWh0 = offW;
  size_t offWl0 = offWh0 + 256 * 256 * 2;
  size_t offWh1 = offWl0 + 256 * 256 * 2;
  size_t offWl1 = offWh1 + 256 * 256 * 2;
  size_t offWh2 = offWl1 + 256 * 256 * 2;
  size_t offWl2 = offWh2 + 256 * 64 * 2;

  int* edge_src = (int*)(ws + offEdge);
  int* row_start = (int*)(ws + offRow);
  int* cursor = (int*)(ws + offCur);
  int* degO = (int*)(ws + offDegO);
  int* degI = (int*)(ws + offDegI);
  float* ns = (float*)(ws + offNs);
  float* nd = (float*)(ws + offNd);
  int* partials = (int*)(ws + offPart);
  double* stats = (double*)(ws + offStats);
  unsigned short* Wh0 = (unsigned short*)(ws + offWh0);
  unsigned short* Wl0 = (unsigned short*)(ws + offWl0);
  unsigned short* Wh1 = (unsigned short*)(ws + offWh1);
  unsigned short* Wl1 = (unsigned short*)(ws + offWl1);
  unsigned short* Wh2 = (unsigned short*)(ws + offWh2);
  unsigned short* Wl2 = (unsigned short*)(ws + offWl2);

  // Ping-pong aliasing (R1/R2, each 102.4MB):
  __half* Ah0 = (__half*)R1;                          // prescale out
  unsigned short* Bhi0 = (unsigned short*)R2;         // spmm0 out planes
  unsigned short* Blo0 = Bhi0 + (size_t)N * 256;
  float* A0 = (float*)R1;                             // gemm0 out (f32)
  __half* Ah1 = (__half*)R2;                          // normp0 out
  unsigned short* Bhi1 = (unsigned short*)R1;         // spmm1 out planes
  unsigned short* Blo1 = Bhi1 + (size_t)N * 256;
  float* A1 = (float*)R2;                             // gemm1 out (f32)
  unsigned short* A2hi = (unsigned short*)R1;         // normp1 out planes
  unsigned short* A2lo = A2hi + (size_t)N * 256;
  __half* Gh = (__half*)R2;                           // gemm2 out (fp16)

  const int eb = (E + 255) / 256;
  const int nb = (N + 255) / 256;
  const int sb = (N + 2047) / 2048;
  const int hq = (N * 32 + 255) / 256;   // 8-elem threads over [N,256]
  const int wb = (N + 3) / 4;            // one wave per row
  const int gx = (N + 63) / 64;
  const double inv_count = 1.0 / ((double)N * 256.0);

  hipMemsetAsync(degO, 0, (size_t)N * 8, stream);
  hipMemsetAsync(stats, 0, 4 * sizeof(double), stream);

  prepw_k<<<256, 256, 0, stream>>>(W0, Wh0, Wl0, 256, 8);
  prepw_k<<<256, 256, 0, stream>>>(W1, Wh1, Wl1, 256, 8);
  prepw_k<<<64, 256, 0, stream>>>(W2, Wh2, Wl2, 256, 6);

  degrees_k<<<eb, 256, 0, stream>>>(src, dst, degO, degI, E);
  norm_k<<<nb, 256, 0, stream>>>(degO, degI, ns, nd, N);
  scan1_k<<<sb, 256, 0, stream>>>(degI, row_start, partials, N);
  scan2_k<<<1, 64, 0, stream>>>(partials, sb);
  scan3_k<<<nb, 256, 0, stream>>>(row_start, cursor, partials, N, E);
  fill_k<<<eb, 256, 0, stream>>>(src, dst, cursor, edge_src, E);

  // ---- layer 0 ----
  prescale_h_k<<<hq, 256, 0, stream>>>(features, ns, Ah0, N);
  spmm256_h_k<<<wb, 256, 0, stream>>>(Ah0, row_start, edge_src, nd, Bhi0, Blo0, N);
  gemm_k<true, false><<<dim3(gx, 4), 256, 0, stream>>>(Bhi0, Blo0, Wh0, Wl0, b0,
                                                       A0, nullptr, N, 256, stats);
  normp_h_k<<<hq, 256, 0, stream>>>(A0, ns, stats, inv_count, Ah1, N);

  // ---- layer 1 ----
  spmm256_h_k<<<wb, 256, 0, stream>>>(Ah1, row_start, edge_src, nd, Bhi1, Blo1, N);
  gemm_k<true, false><<<dim3(gx, 4), 256, 0, stream>>>(Bhi1, Blo1, Wh1, Wl1, b1,
                                                       A1, nullptr, N, 256, stats + 2);
  normp_p_k<<<hq, 256, 0, stream>>>(A1, ns, stats + 2, inv_count, A2hi, A2lo, N);

  // ---- layer 2: GEMM first (W commutes with aggregation), then F=64 SpMM ----
  gemm_k<false, true><<<dim3(gx, 1), 256, 0, stream>>>(A2hi, A2lo, Wh2, Wl2, nullptr,
                                                       nullptr, Gh, N, 64, nullptr);
  spmm64_h_k<<<wb, 256, 0, stream>>>(Gh, row_start, edge_src, nd, b2, out, N);
}